// Round 13
// baseline (250.963 us; speedup 1.0000x reference)
//
#include <hip/hip_runtime.h>
#include <hip/hip_bf16.h>

// B=64, S=512, E=256, D=512
#define EDIM 256
#define SDIM 512
#define DDIM 512

// ws byte offsets (R13: Xp eliminated — mega reads X f32 directly)
#define OFF_BFI   0u          // bf16 frag-major interior weights = 1,572,864 B
#define OFF_BFT   1572864u    // bf16 frag-major tail (W1) weights = 262,144 B
#define OFF_CORR  1835008u    // f32  [512][128]  (layout [d][b*2+s])
#define OFF_BI    2097152u    // f32  [512]
#define OFF_ZERO  2099200u    // 4 KB zeros (A-staging source for padded rows)

// prep grid partition (CVT pass deleted: 8720 -> 4608 blocks)
#define WB_BLOCKS   512       // weight blocks (one per d)
#define PREP_BLOCKS 4608      // + 4096 corr blocks (512 d x 8 b-chunks)

typedef __attribute__((ext_vector_type(8))) __bf16 bf16x8;
typedef __attribute__((ext_vector_type(4))) float  f32x4;
typedef __attribute__((ext_vector_type(8))) unsigned short ushort8v;

__device__ __forceinline__ unsigned short f2bf(float f) {
    unsigned int u = __float_as_uint(f);
    u = (u + 0x7fffu + ((u >> 16) & 1u)) >> 16;   // RNE (bit-identical to old prep cvt)
    return (unsigned short)u;
}

// ============ launch 1: weight-fragment + edge-correction (no CVT) ============
__global__ __launch_bounds__(256) void prep_all(
    const float* __restrict__ X,
    const float* __restrict__ W1, const float* __restrict__ b1,
    const float* __restrict__ W2, const float* __restrict__ b2,
    const float* __restrict__ W3, const float* __restrict__ b3,
    const float* __restrict__ W4, const float* __restrict__ b4,
    char* __restrict__ wsb)
{
    const int tid = threadIdx.x;

    if (blockIdx.x < WB_BLOCKS) {
        // ---- combined weights -> fragment-major, one block per d (coalesced reads) ----
        // G_int[d][k], k = shift*256 + e, shift 0..5 (delta grouping, R0 derivation)
        const int d = blockIdx.x;            // 0..511
        const int e = tid;                   // 0..255
        const int de = d * EDIM + e;

        if (blockIdx.x == 0)                 // zero page for mega's padded-row staging
            *(float4*)(wsb + OFF_ZERO + tid * 16) = make_float4(0.f, 0.f, 0.f, 0.f);

        const float w1  = W1[de];
        const float w20 = W2[de * 2 + 0], w21 = W2[de * 2 + 1];
        const float w30 = W3[de * 3 + 0], w31 = W3[de * 3 + 1], w32 = W3[de * 3 + 2];
        const float w40 = W4[de * 4 + 0], w41 = W4[de * 4 + 1], w42 = W4[de * 4 + 2], w43 = W4[de * 4 + 3];

        float g[6];
        g[0] = w40;
        g[1] = w30 + w40 + w41;
        g[2] = w1 + w20 + w30 + w31 + w40 + w41 + w42;
        g[3] = w21 + w31 + w32 + w41 + w42 + w43;
        g[4] = w32 + w42 + w43;
        g[5] = w43;

        const int fm = d & 15, t = (d >> 4) & 3, h = (d >> 6) & 1, c = d >> 7;
        const int hi = (e >> 3) & 3, j = e & 7, eb = e >> 5;
        char* ibase = wsb + OFF_BFI + (size_t)((c * 2 + h) * 48) * 4096
                    + t * 1024 + hi * 256 + fm * 16 + j * 2;
#pragma unroll
        for (int s = 0; s < 6; ++s)
            *(unsigned short*)(ibase + (size_t)(s * 8 + eb) * 4096) = f2bf(g[s]);

        *(unsigned short*)(wsb + OFF_BFT + (size_t)((c * 2 + h) * 8 + eb) * 4096
                           + t * 1024 + hi * 256 + fm * 16 + j * 2) = f2bf(w1);

        if (e == 0)
            ((float*)(wsb + OFF_BI))[d] = b1[d] + b2[d] + 2.0f * b3[d] + 3.0f * b4[d];
        return;
    }

    // ---- edge correction, block = (d, 8-batch chunk); coalesced weight rows.
    {
        __shared__ float cls[16];
        const int cb = blockIdx.x - WB_BLOCKS;   // 0..4095
        const int d  = cb >> 3;                  // 0..511
        const int bq = (cb & 7) * 8;             // batch chunk base
        const int e  = tid;                      // 0..255

        if (tid < 16) cls[tid] = 0.f;

        const float w31 = W3[(size_t)d * 768 + 3 * e + 1];
        const float w32 = W3[(size_t)d * 768 + 3 * e + 2];
        const float4 w4v = *(const float4*)(W4 + (size_t)d * 1024 + 4 * e);
        const float w41 = w4v.y, w42 = w4v.z, w43 = w4v.w;

        const float c00 = w31 + w41 + w42;
        const float c01 = w32 + w42 + w43;
        const float c02 = w43;
        __syncthreads();

#pragma unroll
        for (int bi = 0; bi < 8; ++bi) {
            const float* xr = X + (size_t)(bq + bi) * (SDIM * EDIM) + e;
            const float x0 = xr[0], x1 = xr[EDIM], x2 = xr[2 * EDIM];
            float a0 = c00 * x0 + c01 * x1 + c02 * x2;
            float a1 = w41 * x0 + w42 * x1 + w43 * x2;
#pragma unroll
            for (int off = 32; off >= 1; off >>= 1) {
                a0 += __shfl_xor(a0, off, 64);
                a1 += __shfl_xor(a1, off, 64);
            }
            if ((tid & 63) == 0) {
                atomicAdd(&cls[bi * 2 + 0], a0);
                atomicAdd(&cls[bi * 2 + 1], a1);
            }
        }
        __syncthreads();

        if (tid < 16) {
            const int s = tid & 1;
            const float bc = s ? b4[d] : (b3[d] + 2.f * b4[d]);
            ((float*)(wsb + OFF_CORR))[(size_t)d * 128 + bq * 2 + tid] = -cls[tid] - bc;
        }
    }
}

// ============ launch 2: fused-cvt GEMM (R13) ============
// A staged global(f32)->reg->cvt(f2bf)->ds_write (GLL can't convert). Same
// 4-buffer/1-barrier frame, vmcnt(8) = next phase's {4 A + 4 B} loads in
// flight across every barrier (never 0 in-loop). Write q(p+1) / read q(p) /
// last-read q(p-3): 3 barriers of separation. Padded rows (s<2) read a ws
// zero page via per-phase pointer select. LDS bits identical to R12's Xp
// path (same f2bf, same XOR slot) -> absmax unchanged. Epilogue = R12's
// LDS-transpose + NT f32x4 stores (+ top guard barrier).
#define TSTRIDE 132   // f32 stride of transpose tile rows (528 B, 16B-aligned)

__global__ __launch_bounds__(512, 4) void mega(
    const float* __restrict__ X,
    const char* __restrict__ wsb,
    const float* __restrict__ b1,
    float* __restrict__ out)
{
    __shared__ __align__(16) char smem[67584];   // max(4x16KB A-buffers, 128x132 f32 tile)
    const int id  = blockIdx.x;                  // natural: XCD = id%8 = strip%8 (A-locality, R6)
    const int strip = id & 127;                  // 128 strips x 128 rows
    const int c     = id >> 7;                   // col block 0..3
    const int col0  = c * 128;
    const int tid = threadIdx.x;
    const int w = tid >> 6, l = tid & 63;

    char* q0 = smem;
    char* q1 = smem + 16384;
    char* q2 = smem + 32768;
    char* q3 = smem + 49152;

    // A staging: wave w owns rows [16w,16w+16): chunk0 = row 16w+(l>>3),
    // chunk1 = +8. Per lane per phase: 8 f32 per chunk (32 B, 2 dwordx4).
    const int rbase = strip * 128 + 16 * w + (l >> 3);
    const int bb0  = rbase >> 8;                 // batch
    const int ssl0 = rbase & 255;                // s within half
    const int qm_int = 2 - ssl0;                 // interior: phase p valid iff (p>>2) >= qm
    const int wrow = (16 * w + (l >> 3)) * 128 + ((l & 7) ^ (l >> 3)) * 16;  // swizzled dest

    const int wrg = (w >> 2) * 64;               // wave row-group (0 or 64)
    const int qc  = w & 3;                       // wave col-quarter (32 cols)
    const int fm  = l & 15;
    const int hi4 = l >> 4;
    const int rs0 = ((hi4)     ^ (fm & 7)) * 16; // read slots (match write XOR)
    const int rs1 = ((4 + hi4) ^ (fm & 7)) * 16;

    const int hq   = qc >> 1;
    const int toff = (qc & 1) * 2048;
    const char* bfi = wsb + OFF_BFI + (size_t)(c * 2 + hq) * (48 * 4096) + toff + l * 16;
    const char* bft = wsb + OFF_BFT + (size_t)(c * 2 + hq) * (8 * 4096)  + toff + l * 16;
    const char* zb  = wsb + OFF_ZERO + (l & 7) * 32;   // zero source for padded rows

    f32x4 acc[4][2];
    const char *ga0, *ga1;

    auto LOADB = [&](bf16x8 (&dst)[4], const char* base, int ph) {
#pragma unroll
        for (int ks = 0; ks < 2; ++ks)
#pragma unroll
            for (int j = 0; j < 2; ++j)
                dst[ks * 2 + j] = *(const bf16x8*)(base + (size_t)(2 * ph + ks) * 4096 + j * 1024);
    };
    auto LOADA = [&](f32x4 (&d)[4], int p, int qm) {
        const char* s0 = ((p >> 2) >= qm) ? ga0 : zb;  // chunk0 may be a padded row
        d[0] = *(const f32x4*)(s0);
        d[1] = *(const f32x4*)(s0 + 16);
        d[2] = *(const f32x4*)(ga1);                   // chunk1 rows always valid
        d[3] = *(const f32x4*)(ga1 + 16);
        ga0 += 256; ga1 += 256;                        // +64 f32/phase, linear walk
    };
    auto WRA = [&](const f32x4 (&a)[4], char* buf) {
        ushort8v u0, u1;
#pragma unroll
        for (int j = 0; j < 4; ++j) {
            u0[j]     = f2bf(a[0][j]);
            u0[4 + j] = f2bf(a[1][j]);
            u1[j]     = f2bf(a[2][j]);
            u1[4 + j] = f2bf(a[3][j]);
        }
        *(ushort8v*)(buf + wrow)        = u0;
        *(ushort8v*)(buf + wrow + 1024) = u1;
    };
    auto COMP = [&](const char* buf, const bf16x8 (&b)[4]) {
#pragma unroll
        for (int ks = 0; ks < 2; ++ks) {
            bf16x8 af[4];
            const int rs = ks ? rs1 : rs0;
#pragma unroll
            for (int t = 0; t < 4; ++t)
                af[t] = *(const bf16x8*)(buf + (wrg + t * 16 + fm) * 128 + rs);
#pragma unroll
            for (int i = 0; i < 4; ++i)
#pragma unroll
                for (int j = 0; j < 2; ++j)
                    acc[i][j] = __builtin_amdgcn_mfma_f32_16x16x32_bf16(af[i], b[ks * 2 + j], acc[i][j], 0, 0, 0);
        }
    };

#define VM8   asm volatile("s_waitcnt vmcnt(8)" ::: "memory");
#define VM0   asm volatile("s_waitcnt vmcnt(0)" ::: "memory");
#define LK0B  asm volatile("s_waitcnt lgkmcnt(0)" ::: "memory"); __builtin_amdgcn_s_barrier();
#define DO_COMP(Q, B) __builtin_amdgcn_s_setprio(1); COMP(Q, B); __builtin_amdgcn_s_setprio(0);

    auto GEMM = [&](const char* bbase, int np, int qm) {   // np % 4 == 0, np >= 4
        bf16x8 B0[4], B1[4], B2[4], B3[4];
        f32x4 Aev[4], Aod[4];
        LOADA(Aev, 0, qm); LOADB(B0, bbase, 0);
        LOADA(Aod, 1, qm); LOADB(B1, bbase, 1);            // 16 outstanding
        VM8;                                               // phase 0's 8 landed
        WRA(Aev, q0);
        LK0B;                                              // q0 ready
#pragma unroll 1
        for (int p = 0; p + 4 < np; p += 4) {
            LOADA(Aev, p + 2, qm); LOADB(B2, bbase, p + 2);
            VM8; WRA(Aod, q1); LK0B; DO_COMP(q0, B0);
            LOADA(Aod, p + 3, qm); LOADB(B3, bbase, p + 3);
            VM8; WRA(Aev, q2); LK0B; DO_COMP(q1, B1);
            LOADA(Aev, p + 4, qm); LOADB(B0, bbase, p + 4);
            VM8; WRA(Aod, q3); LK0B; DO_COMP(q2, B2);
            LOADA(Aod, p + 5, qm); LOADB(B1, bbase, p + 5);
            VM8; WRA(Aev, q0); LK0B; DO_COMP(q3, B3);
        }
        // final 4 phases (p = np-4): stage only np-2, np-1
        LOADA(Aev, np - 2, qm); LOADB(B2, bbase, np - 2);
        VM8; WRA(Aod, q1); LK0B; DO_COMP(q0, B0);
        LOADA(Aod, np - 1, qm); LOADB(B3, bbase, np - 1);
        VM8; WRA(Aev, q2); LK0B; DO_COMP(q1, B1);
        VM0; WRA(Aod, q3); LK0B; DO_COMP(q2, B2);
        DO_COMP(q3, B3);                                   // q3 written before previous barrier
    };

    // ---- epilogue: acc -> LDS transpose tile -> f32x4 NT stores ----
    auto EPI = [&](int s_base, bool with_corr) {
        LK0B;                                              // GEMM LDS reads drained before T reuse
        const float* bias = with_corr ? (const float*)(wsb + OFF_BI) : b1;
        const float* corr = (const float*)(wsb + OFF_CORR);   // [d][b*2+s]
        const int ocol = col0 + qc * 32 + fm;
        const int rq   = hi4 * 4;
        float bv[2];
#pragma unroll
        for (int j = 0; j < 2; ++j) bv[j] = bias[ocol + j * 16];

        float* T = (float*)smem;
#pragma unroll
        for (int i = 0; i < 4; ++i) {
#pragma unroll
            for (int r = 0; r < 4; ++r) {
                const int row = wrg + i * 16 + rq + r;        // 0..127
                const int rr  = strip * 128 + row;
                const int ssl = rr & 255;
                const int bb  = rr >> 8;
#pragma unroll
                for (int j = 0; j < 2; ++j) {
                    float v = acc[i][j][r] + bv[j];
                    if (with_corr && ssl < 2)
                        v += corr[(size_t)(ocol + j * 16) * 128 + bb * 2 + ssl];
                    T[row * TSTRIDE + qc * 32 + j * 16 + fm] = v;
                }
            }
        }
        LK0B;
        const int c16   = l & 31;              // 16B chunk within 512B row-slice
        const int rhalf = l >> 5;
#pragma unroll
        for (int itr = 0; itr < 8; ++itr) {
            const int row = w * 16 + 2 * itr + rhalf;
            const f32x4 v = *(const f32x4*)(T + row * TSTRIDE + c16 * 4);
            const int rr  = strip * 128 + row;
            const int ssl = rr & 255;
            const int bb  = rr >> 8;
            float* op = out + ((size_t)(bb * SDIM + s_base + ssl)) * DDIM + col0 + c16 * 4;
            __builtin_nontemporal_store(v, (f32x4*)op);
        }
        LK0B;                                  // LDS safe for next GEMM staging
    };

    // ---- interior: A row (b,s) = X[b][s-2 .. s+3][:] flattened (2 zero rows), 24 phases ----
#pragma unroll
    for (int i = 0; i < 4; ++i)
#pragma unroll
        for (int j = 0; j < 2; ++j) acc[i][j] = (f32x4){0.f, 0.f, 0.f, 0.f};
    ga0 = (const char*)(X + (ptrdiff_t)(bb0 * SDIM + ssl0 - 2) * EDIM + (l & 7) * 8);
    ga1 = (const char*)(X + (ptrdiff_t)(bb0 * SDIM + ssl0 + 6) * EDIM + (l & 7) * 8);
    GEMM(bfi, 24, qm_int);
    EPI(0, true);

    // ---- tail: s in [256,512), unigram only: A row = X[b][s][:], 4 phases ----
#pragma unroll
    for (int i = 0; i < 4; ++i)
#pragma unroll
        for (int j = 0; j < 2; ++j) acc[i][j] = (f32x4){0.f, 0.f, 0.f, 0.f};
    ga0 = (const char*)(X + (size_t)(bb0 * SDIM + 256 + ssl0) * EDIM + (l & 7) * 8);
    ga1 = (const char*)(X + (size_t)(bb0 * SDIM + 264 + ssl0) * EDIM + (l & 7) * 8);
    GEMM(bft, 4, -1000);
    EPI(256, false);
}

extern "C" void kernel_launch(void* const* d_in, const int* in_sizes, int n_in,
                              void* d_out, int out_size, void* d_ws, size_t ws_size,
                              hipStream_t stream)
{
    const float* X  = (const float*)d_in[0];
    const float* W1 = (const float*)d_in[1];
    const float* b1 = (const float*)d_in[2];
    const float* W2 = (const float*)d_in[3];
    const float* b2 = (const float*)d_in[4];
    const float* W3 = (const float*)d_in[5];
    const float* b3 = (const float*)d_in[6];
    const float* W4 = (const float*)d_in[7];
    const float* b4 = (const float*)d_in[8];
    float* out = (float*)d_out;
    char*  wsb = (char*)d_ws;

    prep_all<<<dim3(PREP_BLOCKS), dim3(256), 0, stream>>>(X, W1, b1, W2, b2, W3, b3, W4, b4, wsb);

    mega<<<dim3(512), dim3(512), 0, stream>>>(X, wsb, b1, out);
}